// Round 12
// baseline (182.743 us; speedup 1.0000x reference)
//
#include <hip/hip_runtime.h>

#define VOCAB   100000
#define EMB     128
#define CLASSES 1000
#define BATCH   16384
#define SEQLEN  200

typedef short bf16x8 __attribute__((ext_vector_type(8)));
typedef float f32x4  __attribute__((ext_vector_type(4)));

__device__ __forceinline__ unsigned short f32_to_bf16(float f) {
    unsigned int u = __builtin_bit_cast(unsigned int, f);
    u += 0x7fffu + ((u >> 16) & 1u);   // round-to-nearest-even
    return (unsigned short)(u >> 16);
}
// signed-byte extract -> float
__device__ __forceinline__ float sb(unsigned int w, int sh) {
    return (float)(int)(signed char)((w >> sh) & 0xffu);
}

// Blocks [0,6250): quantize emb rows to int8 + per-row scale (amax/127).
// Blocks [6250,6313): convert fc_w to bf16.   (UNCHANGED from round 4.)
__global__ __launch_bounds__(256) void convert_emb_i8(const float* __restrict__ emb,
                                                      const float* __restrict__ fcw,
                                                      unsigned char* __restrict__ e8,
                                                      float* __restrict__ scl,
                                                      unsigned short* __restrict__ wb) {
    if (blockIdx.x < 6250) {
        const int row = blockIdx.x * 16 + (threadIdx.x >> 4);
        const int c8  = (threadIdx.x & 15) * 8;
        const float* r = emb + (long)row * EMB + c8;
        float4 v0 = *(const float4*)(r);
        float4 v1 = *(const float4*)(r + 4);
        float m = fmaxf(fmaxf(fmaxf(fabsf(v0.x), fabsf(v0.y)), fmaxf(fabsf(v0.z), fabsf(v0.w))),
                        fmaxf(fmaxf(fabsf(v1.x), fabsf(v1.y)), fmaxf(fabsf(v1.z), fabsf(v1.w))));
        m = fmaxf(m, __shfl_xor(m, 1));
        m = fmaxf(m, __shfl_xor(m, 2));
        m = fmaxf(m, __shfl_xor(m, 4));
        m = fmaxf(m, __shfl_xor(m, 8));          // all 16 lanes hold row amax
        const float inv = (m > 0.f) ? 127.0f / m : 0.f;
#define Q(x) ((int)fminf(fmaxf(__builtin_rintf((x) * inv), -127.f), 127.f))
        int q0 = Q(v0.x), q1 = Q(v0.y), q2 = Q(v0.z), q3 = Q(v0.w);
        int q4 = Q(v1.x), q5 = Q(v1.y), q6 = Q(v1.z), q7 = Q(v1.w);
#undef Q
        uint2 o;
        o.x = (unsigned int)(q0 & 255) | ((unsigned int)(q1 & 255) << 8) |
              ((unsigned int)(q2 & 255) << 16) | ((unsigned int)(q3 & 255) << 24);
        o.y = (unsigned int)(q4 & 255) | ((unsigned int)(q5 & 255) << 8) |
              ((unsigned int)(q6 & 255) << 16) | ((unsigned int)(q7 & 255) << 24);
        *(uint2*)(e8 + (long)row * EMB + c8) = o;
        if ((threadIdx.x & 15) == 0) scl[row] = m * (1.0f / 127.0f);
    } else {
        long i = (((long)blockIdx.x - 6250) * 256 + threadIdx.x) * 8;
        if (i >= (long)CLASSES * EMB) return;
        float4 v0 = *(const float4*)(fcw + i);
        float4 v1 = *(const float4*)(fcw + i + 4);
        uint4 o;
        o.x = (unsigned int)f32_to_bf16(v0.x) | ((unsigned int)f32_to_bf16(v0.y) << 16);
        o.y = (unsigned int)f32_to_bf16(v0.z) | ((unsigned int)f32_to_bf16(v0.w) << 16);
        o.z = (unsigned int)f32_to_bf16(v1.x) | ((unsigned int)f32_to_bf16(v1.y) << 16);
        o.w = (unsigned int)f32_to_bf16(v1.z) | ((unsigned int)f32_to_bf16(v1.w) << 16);
        *(uint4*)(wb + i) = o;
    }
}

// FUSED pool+gemm, v7: bucketed token-range passes + 8-DEEP gathers.
// R11 post-mortem: locality worked (FETCH 158->61 MB) but the pool became
// latency-bound -- I had silently cut the pipeline to 4-deep and put an
// LDS list-read in front of every gather (91.7 us, nothing saturated:
// 1.46 TB/s, VALUBusy 46%).  v7 keeps the bucketed structure verbatim and
// restores the R9-proven 8-deep issue: 32-token chunks, 8 independent LDS
// index reads then 8 gathers in flight.  Pad slots (~24%) gather row 0
// (L1-hot) with ms=0 -- near-free.  Everything else frozen from R11.
__global__ __launch_bounds__(1024, 4) void pool_gemm_i8(const int* __restrict__ seq,
                                                        const unsigned char* __restrict__ e8,
                                                        const float* __restrict__ scl,
                                                        const unsigned short* __restrict__ fcw,
                                                        const float* __restrict__ fcb,
                                                        float* __restrict__ out) {
    __shared__ unsigned short Asub[64][136];     // 17.4 KB
    __shared__ int toklist[64 * 3 * 128];        // [bag][pass][slot] 98.3 KB (cap 128 ~ 9 sigma)

    const int lane = threadIdx.x & 63;
    const int wid  = threadIdx.x >> 6;           // 0..15
    const int quad = lane >> 4;
    const int dsub = (lane & 15) * 8;
    const int bbase = blockIdx.x * 64;

    // ---------- bucket: partition each bag's tokens by value range ----------
    int cnt[4][3];
    const unsigned long long lt = (1ull << lane) - 1ull;
#pragma unroll
    for (int j = 0; j < 4; ++j) {
        const int bagL = wid * 4 + j;
        const int* srow = seq + (long)(bbase + bagL) * SEQLEN;
        int tok0 = srow[lane];
        int tok1 = srow[lane + 64];
        int tok2 = srow[lane + 128];
        int tok3 = (lane < 8) ? srow[lane + 192] : 0;
        int* lst0 = &toklist[(bagL * 3 + 0) << 7];
        int* lst1 = &toklist[(bagL * 3 + 1) << 7];
        int* lst2 = &toklist[(bagL * 3 + 2) << 7];
        int o0 = 0, o1 = 0, o2 = 0;
#define BCHUNK(TK, VALID)                                                     \
        {                                                                     \
            const int p = (TK) / 33334;                                       \
            unsigned long long m0 = __ballot((VALID) && p == 0);              \
            unsigned long long m1 = __ballot((VALID) && p == 1);              \
            unsigned long long m2 = __ballot((VALID) && p == 2);              \
            if (VALID) {                                                      \
                int pos = (p == 0) ? (o0 + (int)__popcll(m0 & lt))            \
                        : (p == 1) ? (o1 + (int)__popcll(m1 & lt))            \
                                   : (o2 + (int)__popcll(m2 & lt));           \
                if (pos > 127) pos = 127;                                     \
                int* seg = (p == 0) ? lst0 : (p == 1) ? lst1 : lst2;          \
                seg[pos] = (TK);                                              \
            }                                                                 \
            o0 += (int)__popcll(m0); o1 += (int)__popcll(m1);                 \
            o2 += (int)__popcll(m2);                                          \
        }
        BCHUNK(tok0, true)
        BCHUNK(tok1, true)
        BCHUNK(tok2, true)
        BCHUNK(tok3, (lane < 8))
#undef BCHUNK
        cnt[j][0] = (o0 < 128) ? o0 : 128;
        cnt[j][1] = (o1 < 128) ? o1 : 128;
        cnt[j][2] = (o2 < 128) ? o2 : 128;
    }

    // ---------- pool: 3 locality passes, 8-deep branch-free gathers ----------
    float acc[4][8];
#pragma unroll
    for (int j = 0; j < 4; ++j)
#pragma unroll
        for (int k = 0; k < 8; ++k) acc[j][k] = 0.f;

    // ISS: clamped LDS token read, select-masked (no branch), unconditional
    // gather (pad slots hit hot row 0), scale load.
#define ISS(G, T, U, S)                                                       \
    {                                                                         \
        const int idx = base + 4 * (G) + quad;                                \
        int tki = lst[(idx < n) ? idx : 0];                                   \
        T = (idx < n) ? tki : 0;                                              \
        U = *(const uint2*)(e8 + (long)T * EMB + dsub);                       \
        S = scl[T];                                                           \
    }
#define ACCM(J, T, U, S)                                                      \
    {                                                                         \
        float ms = ((T) != 0) ? (S) : 0.0f;                                   \
        acc[J][0] += ms * sb(U.x, 0);  acc[J][1] += ms * sb(U.x, 8);          \
        acc[J][2] += ms * sb(U.x, 16); acc[J][3] += ms * sb(U.x, 24);         \
        acc[J][4] += ms * sb(U.y, 0);  acc[J][5] += ms * sb(U.y, 8);          \
        acc[J][6] += ms * sb(U.y, 16); acc[J][7] += ms * sb(U.y, 24);         \
    }

#pragma unroll 1
    for (int p = 0; p < 3; ++p) {
        __syncthreads();                          // phase-align waves on the slice
#pragma unroll
        for (int j = 0; j < 4; ++j) {
            const int bagL = wid * 4 + j;
            const int* lst = &toklist[(bagL * 3 + p) << 7];
            const int n = cnt[j][p];
            const int nch = (n + 31) >> 5;        // 32-token chunks, 8-deep pipeline
#pragma unroll 1
            for (int ch = 0; ch < nch; ++ch) {
                const int base = ch << 5;
                int t0, t1, t2, t3, t4, t5, t6, t7;
                uint2 u0, u1, u2, u3, u4, u5, u6, u7;
                float s0, s1, s2, s3, s4, s5, s6, s7;
                ISS(0, t0, u0, s0)
                ISS(1, t1, u1, s1)
                ISS(2, t2, u2, s2)
                ISS(3, t3, u3, s3)
                ISS(4, t4, u4, s4)
                ISS(5, t5, u5, s5)
                ISS(6, t6, u6, s6)
                ISS(7, t7, u7, s7)
                ACCM(j, t0, u0, s0)
                ACCM(j, t1, u1, s1)
                ACCM(j, t2, u2, s2)
                ACCM(j, t3, u3, s3)
                ACCM(j, t4, u4, s4)
                ACCM(j, t5, u5, s5)
                ACCM(j, t6, u6, s6)
                ACCM(j, t7, u7, s7)
            }
        }
    }
#undef ISS
#undef ACCM

    // ---------- reduce across quads, park pooled rows in LDS ----------
#pragma unroll
    for (int j = 0; j < 4; ++j) {
        float a0 = acc[j][0], a1 = acc[j][1], a2 = acc[j][2], a3 = acc[j][3];
        float a4 = acc[j][4], a5 = acc[j][5], a6 = acc[j][6], a7 = acc[j][7];
        a0 += __shfl_xor(a0, 16); a1 += __shfl_xor(a1, 16);
        a2 += __shfl_xor(a2, 16); a3 += __shfl_xor(a3, 16);
        a4 += __shfl_xor(a4, 16); a5 += __shfl_xor(a5, 16);
        a6 += __shfl_xor(a6, 16); a7 += __shfl_xor(a7, 16);
        a0 += __shfl_xor(a0, 32); a1 += __shfl_xor(a1, 32);
        a2 += __shfl_xor(a2, 32); a3 += __shfl_xor(a3, 32);
        a4 += __shfl_xor(a4, 32); a5 += __shfl_xor(a5, 32);
        a6 += __shfl_xor(a6, 32); a7 += __shfl_xor(a7, 32);
        if (lane < 16) {
            uint4 o;
            o.x = (unsigned int)f32_to_bf16(a0) | ((unsigned int)f32_to_bf16(a1) << 16);
            o.y = (unsigned int)f32_to_bf16(a2) | ((unsigned int)f32_to_bf16(a3) << 16);
            o.z = (unsigned int)f32_to_bf16(a4) | ((unsigned int)f32_to_bf16(a5) << 16);
            o.w = (unsigned int)f32_to_bf16(a6) | ((unsigned int)f32_to_bf16(a7) << 16);
            *(uint4*)(&Asub[wid * 4 + j][dsub]) = o;
        }
    }

    __syncthreads();

    // ---------- phase 2: 64x1000 GEMM, 4 A-tiles/wave reg-blocked (frozen, R9) ----------
    const int arow = lane & 15;
    const int koff = quad * 8;
#define LDA(Aa, ROWOFF)                                                        \
    bf16x8 Aa##0 = *(const bf16x8*)(&Asub[(ROWOFF) + arow][koff + 0]);         \
    bf16x8 Aa##1 = *(const bf16x8*)(&Asub[(ROWOFF) + arow][koff + 32]);        \
    bf16x8 Aa##2 = *(const bf16x8*)(&Asub[(ROWOFF) + arow][koff + 64]);        \
    bf16x8 Aa##3 = *(const bf16x8*)(&Asub[(ROWOFF) + arow][koff + 96]);
    LDA(A0_, 0) LDA(A1_, 16) LDA(A2_, 32) LDA(A3_, 48)
#undef LDA

    int t = wid;
    int cc = t * 16 + (lane & 15);
    const unsigned short* wr = fcw + (long)((cc < CLASSES) ? cc : 0) * EMB + koff;
    bf16x8 w0 = *(const bf16x8*)(wr + 0 * 32);
    bf16x8 w1 = *(const bf16x8*)(wr + 1 * 32);
    bf16x8 w2 = *(const bf16x8*)(wr + 2 * 32);
    bf16x8 w3 = *(const bf16x8*)(wr + 3 * 32);

#pragma unroll 1
    while (t < 63) {
        bf16x8 c0 = w0, c1 = w1, c2 = w2, c3 = w3;
        const int ccNow = cc;
        t += 16;
        if (t < 63) {                            // prefetch next tile's W-frag
            cc = t * 16 + (lane & 15);
            const unsigned short* wn = fcw + (long)((cc < CLASSES) ? cc : 0) * EMB + koff;
            w0 = *(const bf16x8*)(wn + 0 * 32);
            w1 = *(const bf16x8*)(wn + 1 * 32);
            w2 = *(const bf16x8*)(wn + 2 * 32);
            w3 = *(const bf16x8*)(wn + 3 * 32);
        }
        f32x4 acc0 = {0.f, 0.f, 0.f, 0.f};
        f32x4 acc1 = {0.f, 0.f, 0.f, 0.f};
        f32x4 acc2 = {0.f, 0.f, 0.f, 0.f};
        f32x4 acc3 = {0.f, 0.f, 0.f, 0.f};
        acc0 = __builtin_amdgcn_mfma_f32_16x16x32_bf16(A0_0, c0, acc0, 0, 0, 0);
        acc1 = __builtin_amdgcn_mfma_f32_16x16x32_bf16(A1_0, c0, acc1, 0, 0, 0);
        acc2 = __builtin_amdgcn_mfma_f32_16x16x32_bf16(A2_0, c0, acc2, 0, 0, 0);
        acc3 = __builtin_amdgcn_mfma_f32_16x16x32_bf16(A3_0, c0, acc3, 0, 0, 0);
        acc0 = __builtin_amdgcn_mfma_f32_16x16x32_bf16(A0_1, c1, acc0, 0, 0, 0);
        acc1 = __builtin_amdgcn_mfma_f32_16x16x32_bf16(A1_1, c1, acc1, 0, 0, 0);
        acc2 = __builtin_amdgcn_mfma_f32_16x16x32_bf16(A2_1, c1, acc2, 0, 0, 0);
        acc3 = __builtin_amdgcn_mfma_f32_16x16x32_bf16(A3_1, c1, acc3, 0, 0, 0);
        acc0 = __builtin_amdgcn_mfma_f32_16x16x32_bf16(A0_2, c2, acc0, 0, 0, 0);
        acc1 = __builtin_amdgcn_mfma_f32_16x16x32_bf16(A1_2, c2, acc1, 0, 0, 0);
        acc2 = __builtin_amdgcn_mfma_f32_16x16x32_bf16(A2_2, c2, acc2, 0, 0, 0);
        acc3 = __builtin_amdgcn_mfma_f32_16x16x32_bf16(A3_2, c2, acc3, 0, 0, 0);
        acc0 = __builtin_amdgcn_mfma_f32_16x16x32_bf16(A0_3, c3, acc0, 0, 0, 0);
        acc1 = __builtin_amdgcn_mfma_f32_16x16x32_bf16(A1_3, c3, acc1, 0, 0, 0);
        acc2 = __builtin_amdgcn_mfma_f32_16x16x32_bf16(A2_3, c3, acc2, 0, 0, 0);
        acc3 = __builtin_amdgcn_mfma_f32_16x16x32_bf16(A3_3, c3, acc3, 0, 0, 0);

        if (ccNow < CLASSES) {
            const float bias = fcb[ccNow];
            // C/D: col=lane&15, row=quad*4+r within each 16-row A-tile
            float* orow0 = out + (long)(bbase +  0 + quad * 4) * CLASSES + ccNow;
            float* orow1 = out + (long)(bbase + 16 + quad * 4) * CLASSES + ccNow;
            float* orow2 = out + (long)(bbase + 32 + quad * 4) * CLASSES + ccNow;
            float* orow3 = out + (long)(bbase + 48 + quad * 4) * CLASSES + ccNow;
#pragma unroll
            for (int r = 0; r < 4; ++r) {
                orow0[(long)r * CLASSES] = acc0[r] + bias;
                orow1[(long)r * CLASSES] = acc1[r] + bias;
                orow2[(long)r * CLASSES] = acc2[r] + bias;
                orow3[(long)r * CLASSES] = acc3[r] + bias;
            }
        }
    }
}

// ---------- f32 fallback (workspace too small for the i8 table) ----------
__global__ __launch_bounds__(256) void convert_fcw(const float* __restrict__ fcw,
                                                   unsigned short* __restrict__ wb) {
    long i = ((long)blockIdx.x * 256 + threadIdx.x) * 8;
    if (i >= (long)CLASSES * EMB) return;
    float4 v0 = *(const float4*)(fcw + i);
    float4 v1 = *(const float4*)(fcw + i + 4);
    uint4 o;
    o.x = (unsigned int)f32_to_bf16(v0.x) | ((unsigned int)f32_to_bf16(v0.y) << 16);
    o.y = (unsigned int)f32_to_bf16(v0.z) | ((unsigned int)f32_to_bf16(v0.w) << 16);
    o.z = (unsigned int)f32_to_bf16(v1.x) | ((unsigned int)f32_to_bf16(v1.y) << 16);
    o.w = (unsigned int)f32_to_bf16(v1.z) | ((unsigned int)f32_to_bf16(v1.w) << 16);
    *(uint4*)(wb + i) = o;
}

__global__ __launch_bounds__(256) void bag_pool_f32(const int* __restrict__ seq,
                                                    const float* __restrict__ emb,
                                                    unsigned short* __restrict__ pooled) {
    const int lane = threadIdx.x & 63;
    const int wid  = threadIdx.x >> 6;
    const int b    = blockIdx.x * 4 + wid;
    const int* srow = seq + (long)b * SEQLEN;
    int ids0 = srow[lane];
    int ids1 = srow[lane + 64];
    int ids2 = srow[lane + 128];
    int ids3 = (lane < 8) ? srow[lane + 192] : 0;
    const int half = lane >> 5;
    const int dsub = (lane & 31) * 4;
    float4 acc = {0.f, 0.f, 0.f, 0.f};
#define PAIR_BODY(IDS, Q)                                                   \
    {                                                                       \
        int tok = __shfl((IDS), 2 * (Q) + half);                            \
        if (tok != 0) {                                                     \
            float4 v = *(const float4*)(emb + (long)tok * EMB + dsub);      \
            acc.x += v.x; acc.y += v.y; acc.z += v.z; acc.w += v.w;         \
        }                                                                   \
    }
#pragma unroll 8
    for (int q = 0; q < 32; ++q) PAIR_BODY(ids0, q)
#pragma unroll 8
    for (int q = 0; q < 32; ++q) PAIR_BODY(ids1, q)
#pragma unroll 8
    for (int q = 0; q < 32; ++q) PAIR_BODY(ids2, q)
#pragma unroll
    for (int q = 0; q < 4; ++q)  PAIR_BODY(ids3, q)
#undef PAIR_BODY
    acc.x += __shfl_xor(acc.x, 32);
    acc.y += __shfl_xor(acc.y, 32);
    acc.z += __shfl_xor(acc.z, 32);
    acc.w += __shfl_xor(acc.w, 32);
    if (lane < 32) {
        uint2 o;
        o.x = (unsigned int)f32_to_bf16(acc.x) | ((unsigned int)f32_to_bf16(acc.y) << 16);
        o.y = (unsigned int)f32_to_bf16(acc.z) | ((unsigned int)f32_to_bf16(acc.w) << 16);
        *(uint2*)(pooled + (long)b * EMB + dsub) = o;
    }
}

__global__ __launch_bounds__(256) void bow_gemm(const unsigned short* __restrict__ pooled,
                                                const unsigned short* __restrict__ fcw,
                                                const float* __restrict__ fcb,
                                                float* __restrict__ out) {
    const int lane = threadIdx.x & 63;
    const int wid  = threadIdx.x >> 6;
    const int quad = lane >> 4;
    const int m0   = blockIdx.x * 64 + wid * 16;
    const int mrow = m0 + (lane & 15);
    const int koff = quad * 8;

    const unsigned short* ar = pooled + (long)mrow * EMB + koff;
    bf16x8 a0 = *(const bf16x8*)(ar + 0 * 32);
    bf16x8 a1 = *(const bf16x8*)(ar + 1 * 32);
    bf16x8 a2 = *(const bf16x8*)(ar + 2 * 32);
    bf16x8 a3 = *(const bf16x8*)(ar + 3 * 32);

    int ccur = (blockIdx.y * 21) * 16 + (lane & 15);
    const unsigned short* wr = fcw + (long)((ccur < CLASSES) ? ccur : 0) * EMB + koff;
    bf16x8 w0 = *(const bf16x8*)(wr + 0 * 32);
    bf16x8 w1 = *(const bf16x8*)(wr + 1 * 32);
    bf16x8 w2 = *(const bf16x8*)(wr + 2 * 32);
    bf16x8 w3 = *(const bf16x8*)(wr + 3 * 32);

#pragma unroll 1
    for (int i = 0; i < 21; ++i) {
        bf16x8 c0 = w0, c1 = w1, c2 = w2, c3 = w3;
        const int cc = ccur;
        if (i + 1 < 21) {
            ccur += 16;
            const unsigned short* wn = fcw + (long)((ccur < CLASSES) ? ccur : 0) * EMB + koff;
            w0 = *(const bf16x8*)(wn + 0 * 32);
            w1 = *(const bf16x8*)(wn + 1 * 32);
            w2 = *(const bf16x8*)(wn + 2 * 32);
            w3 = *(const bf16x8*)(wn + 3 * 32);
        }
        f32x4 acc = {0.f, 0.f, 0.f, 0.f};
        acc = __builtin_amdgcn_mfma_f32_16x16x32_bf16(a0, c0, acc, 0, 0, 0);
        acc = __builtin_amdgcn_mfma_f32_16x16x32_bf16(a1, c1, acc, 0, 0, 0);
        acc = __builtin_amdgcn_mfma_f32_16x16x32_bf16(a2, c2, acc, 0, 0, 0);
        acc = __builtin_amdgcn_mfma_f32_16x16x32_bf16(a3, c3, acc, 0, 0, 0);

        if (cc < CLASSES) {
            const float bias = fcb[cc];
            float* orow = out + (long)(m0 + quad * 4) * CLASSES + cc;
#pragma unroll
            for (int r = 0; r < 4; ++r)
                orow[(long)r * CLASSES] = acc[r] + bias;
        }
    }
}

extern "C" void kernel_launch(void* const* d_in, const int* in_sizes, int n_in,
                              void* d_out, int out_size, void* d_ws, size_t ws_size,
                              hipStream_t stream) {
    const int*   seq = (const int*)d_in[0];
    const float* emb = (const float*)d_in[1];   // f32 [VOCAB, EMB]
    const float* fcw = (const float*)d_in[2];   // f32 [CLASSES, EMB]
    const float* fcb = (const float*)d_in[3];   // f32 [CLASSES]
    float*       out = (float*)d_out;           // f32 [BATCH, CLASSES]

    // main-path workspace: scl | e8 | fcw_bf16
    float*          scl      = (float*)d_ws;                              // f32 [VOCAB]      400 KB
    unsigned char*  e8       = (unsigned char*)(scl + VOCAB);             // i8 [VOCAB,EMB]  12.8 MB
    unsigned short* fcw_bf16 = (unsigned short*)(e8 + (long)VOCAB * EMB); // bf16 [CLASSES,EMB] 256 KB

    const size_t need = (size_t)VOCAB * 4 + (size_t)VOCAB * EMB + (size_t)CLASSES * EMB * 2;

    if (ws_size >= need) {
        convert_emb_i8<<<6313, 256, 0, stream>>>(emb, fcw, e8, scl, fcw_bf16);
        pool_gemm_i8<<<BATCH / 64, 1024, 0, stream>>>(seq, e8, scl, fcw_bf16, fcb, out);
    } else {
        unsigned short* pooled  = (unsigned short*)d_ws;              // bf16 [BATCH, EMB] 4 MB
        unsigned short* fcw_bf  = pooled + (long)BATCH * EMB;         // bf16 [CLASSES, EMB]
        convert_fcw<<<63, 256, 0, stream>>>(fcw, fcw_bf);
        bag_pool_f32<<<BATCH / 4, 256, 0, stream>>>(seq, emb, pooled);
        bow_gemm<<<dim3(BATCH / 64, 3), 256, 0, stream>>>(pooled, fcw_bf, fcb, out);
    }
}

// Round 13
// 168.534 us; speedup vs baseline: 1.0843x; 1.0843x over previous
//
#include <hip/hip_runtime.h>

#define VOCAB   100000
#define EMB     128
#define CLASSES 1000
#define BATCH   16384
#define SEQLEN  200

typedef short bf16x8 __attribute__((ext_vector_type(8)));
typedef float f32x4  __attribute__((ext_vector_type(4)));

__device__ __forceinline__ unsigned short f32_to_bf16(float f) {
    unsigned int u = __builtin_bit_cast(unsigned int, f);
    u += 0x7fffu + ((u >> 16) & 1u);   // round-to-nearest-even
    return (unsigned short)(u >> 16);
}
// signed-byte extract -> float
__device__ __forceinline__ float sb(unsigned int w, int sh) {
    return (float)(int)(signed char)((w >> sh) & 0xffu);
}

// Blocks [0,6250): quantize emb rows to int8 + per-row scale (amax/127).
// Blocks [6250,6313): convert fc_w to bf16.
__global__ __launch_bounds__(256) void convert_emb_i8(const float* __restrict__ emb,
                                                      const float* __restrict__ fcw,
                                                      unsigned char* __restrict__ e8,
                                                      float* __restrict__ scl,
                                                      unsigned short* __restrict__ wb) {
    if (blockIdx.x < 6250) {
        const int row = blockIdx.x * 16 + (threadIdx.x >> 4);
        const int c8  = (threadIdx.x & 15) * 8;
        const float* r = emb + (long)row * EMB + c8;
        float4 v0 = *(const float4*)(r);
        float4 v1 = *(const float4*)(r + 4);
        float m = fmaxf(fmaxf(fmaxf(fabsf(v0.x), fabsf(v0.y)), fmaxf(fabsf(v0.z), fabsf(v0.w))),
                        fmaxf(fmaxf(fabsf(v1.x), fabsf(v1.y)), fmaxf(fabsf(v1.z), fabsf(v1.w))));
        m = fmaxf(m, __shfl_xor(m, 1));
        m = fmaxf(m, __shfl_xor(m, 2));
        m = fmaxf(m, __shfl_xor(m, 4));
        m = fmaxf(m, __shfl_xor(m, 8));          // all 16 lanes hold row amax
        const float inv = (m > 0.f) ? 127.0f / m : 0.f;
#define Q(x) ((int)fminf(fmaxf(__builtin_rintf((x) * inv), -127.f), 127.f))
        int q0 = Q(v0.x), q1 = Q(v0.y), q2 = Q(v0.z), q3 = Q(v0.w);
        int q4 = Q(v1.x), q5 = Q(v1.y), q6 = Q(v1.z), q7 = Q(v1.w);
#undef Q
        uint2 o;
        o.x = (unsigned int)(q0 & 255) | ((unsigned int)(q1 & 255) << 8) |
              ((unsigned int)(q2 & 255) << 16) | ((unsigned int)(q3 & 255) << 24);
        o.y = (unsigned int)(q4 & 255) | ((unsigned int)(q5 & 255) << 8) |
              ((unsigned int)(q6 & 255) << 16) | ((unsigned int)(q7 & 255) << 24);
        *(uint2*)(e8 + (long)row * EMB + c8) = o;
        if ((threadIdx.x & 15) == 0) scl[row] = m * (1.0f / 127.0f);
    } else {
        long i = (((long)blockIdx.x - 6250) * 256 + threadIdx.x) * 8;
        if (i >= (long)CLASSES * EMB) return;
        float4 v0 = *(const float4*)(fcw + i);
        float4 v1 = *(const float4*)(fcw + i + 4);
        uint4 o;
        o.x = (unsigned int)f32_to_bf16(v0.x) | ((unsigned int)f32_to_bf16(v0.y) << 16);
        o.y = (unsigned int)f32_to_bf16(v0.z) | ((unsigned int)f32_to_bf16(v0.w) << 16);
        o.z = (unsigned int)f32_to_bf16(v1.x) | ((unsigned int)f32_to_bf16(v1.y) << 16);
        o.w = (unsigned int)f32_to_bf16(v1.z) | ((unsigned int)f32_to_bf16(v1.w) << 16);
        *(uint4*)(wb + i) = o;
    }
}

// FUSED pool+gemm — R9 configuration restored verbatim (best verified:
// kernel 73.2 us, total 169.2).  R10-R12 post-mortems: the pool is bound
// by a ~8.1 TB/s demand-side ceiling for 128B-granule random gather
// (invariant across bf16/i8 formats, byte counts, occupancy, ILP depth);
// cutting L2-miss (FETCH) bytes via token-range locality delivered FETCH
// 158->61 MB but always cost more in issue structure than it saved
// (226 / 91.7 / 97.5 us vs this kernel's 73.2).  64 bags/block, 1024 thr
// (16 waves: full pool concurrency), grid 256; gemm phase reuses each
// W-frag across 4 in-register A-tiles (W L2 traffic 67 MB).
__global__ __launch_bounds__(1024, 4) void pool_gemm_i8(const int* __restrict__ seq,
                                                        const unsigned char* __restrict__ e8,
                                                        const float* __restrict__ scl,
                                                        const unsigned short* __restrict__ fcw,
                                                        const float* __restrict__ fcb,
                                                        float* __restrict__ out) {
    __shared__ unsigned short Asub[64][136];     // 64 pooled rows, +8 pad (17.4 KB)

    const int lane = threadIdx.x & 63;
    const int wid  = threadIdx.x >> 6;           // 0..15
    const int quad = lane >> 4;
    const int dsub = (lane & 15) * 8;
    const int bbase = blockIdx.x * 64;

    // ---------------- phase 1: pool 4 bags per wave, 8-deep branch-free ----------------
#define ISSUE(IDS, G, T, U, S)                                                \
    T = __shfl((IDS), 4 * (G) + quad);                                        \
    U = *(const uint2*)(e8 + (long)T * EMB + dsub);                           \
    S = scl[T];
#define ACCUM(T, U, S)                                                        \
    {                                                                         \
        float ms = (T != 0) ? S : 0.0f;                                       \
        a0 += ms * sb(U.x, 0);  a1 += ms * sb(U.x, 8);                        \
        a2 += ms * sb(U.x, 16); a3 += ms * sb(U.x, 24);                       \
        a4 += ms * sb(U.y, 0);  a5 += ms * sb(U.y, 8);                        \
        a6 += ms * sb(U.y, 16); a7 += ms * sb(U.y, 24);                       \
    }
#define PIPE8(IDS, G0)                                                        \
    {                                                                         \
        int t0, t1, t2, t3, t4, t5, t6, t7;                                   \
        uint2 u0, u1, u2, u3, u4, u5, u6, u7;                                 \
        float s0, s1, s2, s3, s4, s5, s6, s7;                                 \
        ISSUE(IDS, (G0) + 0, t0, u0, s0)                                      \
        ISSUE(IDS, (G0) + 1, t1, u1, s1)                                      \
        ISSUE(IDS, (G0) + 2, t2, u2, s2)                                      \
        ISSUE(IDS, (G0) + 3, t3, u3, s3)                                      \
        ISSUE(IDS, (G0) + 4, t4, u4, s4)                                      \
        ISSUE(IDS, (G0) + 5, t5, u5, s5)                                      \
        ISSUE(IDS, (G0) + 6, t6, u6, s6)                                      \
        ISSUE(IDS, (G0) + 7, t7, u7, s7)                                      \
        ACCUM(t0, u0, s0) ACCUM(t1, u1, s1) ACCUM(t2, u2, s2) ACCUM(t3, u3, s3) \
        ACCUM(t4, u4, s4) ACCUM(t5, u5, s5) ACCUM(t6, u6, s6) ACCUM(t7, u7, s7) \
    }

#pragma unroll 1
    for (int j = 0; j < 4; ++j) {
        const int bagLocal = wid * 4 + j;
        const int* srow = seq + (long)(bbase + bagLocal) * SEQLEN;
        int ids0 = srow[lane];
        int ids1 = srow[lane + 64];
        int ids2 = srow[lane + 128];
        int ids3 = (lane < 8) ? srow[lane + 192] : 0;

        float a0 = 0.f, a1 = 0.f, a2 = 0.f, a3 = 0.f;
        float a4 = 0.f, a5 = 0.f, a6 = 0.f, a7 = 0.f;

        PIPE8(ids0, 0)
        PIPE8(ids0, 8)
        PIPE8(ids1, 0)
        PIPE8(ids1, 8)
        PIPE8(ids2, 0)
        PIPE8(ids2, 8)
        {
            int t0, t1;
            uint2 u0, u1;
            float s0, s1;
            ISSUE(ids3, 0, t0, u0, s0)
            ISSUE(ids3, 1, t1, u1, s1)
            ACCUM(t0, u0, s0) ACCUM(t1, u1, s1)
        }

        a0 += __shfl_xor(a0, 16); a1 += __shfl_xor(a1, 16);
        a2 += __shfl_xor(a2, 16); a3 += __shfl_xor(a3, 16);
        a4 += __shfl_xor(a4, 16); a5 += __shfl_xor(a5, 16);
        a6 += __shfl_xor(a6, 16); a7 += __shfl_xor(a7, 16);
        a0 += __shfl_xor(a0, 32); a1 += __shfl_xor(a1, 32);
        a2 += __shfl_xor(a2, 32); a3 += __shfl_xor(a3, 32);
        a4 += __shfl_xor(a4, 32); a5 += __shfl_xor(a5, 32);
        a6 += __shfl_xor(a6, 32); a7 += __shfl_xor(a7, 32);

        if (lane < 16) {
            uint4 o;
            o.x = (unsigned int)f32_to_bf16(a0) | ((unsigned int)f32_to_bf16(a1) << 16);
            o.y = (unsigned int)f32_to_bf16(a2) | ((unsigned int)f32_to_bf16(a3) << 16);
            o.z = (unsigned int)f32_to_bf16(a4) | ((unsigned int)f32_to_bf16(a5) << 16);
            o.w = (unsigned int)f32_to_bf16(a6) | ((unsigned int)f32_to_bf16(a7) << 16);
            *(uint4*)(&Asub[bagLocal][dsub]) = o;
        }
    }
#undef PIPE8
#undef ACCUM
#undef ISSUE

    __syncthreads();

    // ---------------- phase 2: 64x1000 GEMM, 4 A-tiles/wave reg-blocked ----------------
    const int arow = lane & 15;
    const int koff = quad * 8;
#define LDA(Aa, ROWOFF)                                                        \
    bf16x8 Aa##0 = *(const bf16x8*)(&Asub[(ROWOFF) + arow][koff + 0]);         \
    bf16x8 Aa##1 = *(const bf16x8*)(&Asub[(ROWOFF) + arow][koff + 32]);        \
    bf16x8 Aa##2 = *(const bf16x8*)(&Asub[(ROWOFF) + arow][koff + 64]);        \
    bf16x8 Aa##3 = *(const bf16x8*)(&Asub[(ROWOFF) + arow][koff + 96]);
    LDA(A0_, 0) LDA(A1_, 16) LDA(A2_, 32) LDA(A3_, 48)
#undef LDA

    // 63 class-tiles of 16, round-robin over 16 waves; W-frag loaded ONCE
    // per tile and reused across the 4 A-tiles.
    int t = wid;
    int cc = t * 16 + (lane & 15);
    const unsigned short* wr = fcw + (long)((cc < CLASSES) ? cc : 0) * EMB + koff;
    bf16x8 w0 = *(const bf16x8*)(wr + 0 * 32);
    bf16x8 w1 = *(const bf16x8*)(wr + 1 * 32);
    bf16x8 w2 = *(const bf16x8*)(wr + 2 * 32);
    bf16x8 w3 = *(const bf16x8*)(wr + 3 * 32);

#pragma unroll 1
    while (t < 63) {
        bf16x8 c0 = w0, c1 = w1, c2 = w2, c3 = w3;
        const int ccNow = cc;
        t += 16;
        if (t < 63) {                            // prefetch next tile's W-frag
            cc = t * 16 + (lane & 15);
            const unsigned short* wn = fcw + (long)((cc < CLASSES) ? cc : 0) * EMB + koff;
            w0 = *(const bf16x8*)(wn + 0 * 32);
            w1 = *(const bf16x8*)(wn + 1 * 32);
            w2 = *(const bf16x8*)(wn + 2 * 32);
            w3 = *(const bf16x8*)(wn + 3 * 32);
        }
        f32x4 acc0 = {0.f, 0.f, 0.f, 0.f};
        f32x4 acc1 = {0.f, 0.f, 0.f, 0.f};
        f32x4 acc2 = {0.f, 0.f, 0.f, 0.f};
        f32x4 acc3 = {0.f, 0.f, 0.f, 0.f};
        acc0 = __builtin_amdgcn_mfma_f32_16x16x32_bf16(A0_0, c0, acc0, 0, 0, 0);
        acc1 = __builtin_amdgcn_mfma_f32_16x16x32_bf16(A1_0, c0, acc1, 0, 0, 0);
        acc2 = __builtin_amdgcn_mfma_f32_16x16x32_bf16(A2_0, c0, acc2, 0, 0, 0);
        acc3 = __builtin_amdgcn_mfma_f32_16x16x32_bf16(A3_0, c0, acc3, 0, 0, 0);
        acc0 = __builtin_amdgcn_mfma_f32_16x16x32_bf16(A0_1, c1, acc0, 0, 0, 0);
        acc1 = __builtin_amdgcn_mfma_f32_16x16x32_bf16(A1_1, c1, acc1, 0, 0, 0);
        acc2 = __builtin_amdgcn_mfma_f32_16x16x32_bf16(A2_1, c1, acc2, 0, 0, 0);
        acc3 = __builtin_amdgcn_mfma_f32_16x16x32_bf16(A3_1, c1, acc3, 0, 0, 0);
        acc0 = __builtin_amdgcn_mfma_f32_16x16x32_bf16(A0_2, c2, acc0, 0, 0, 0);
        acc1 = __builtin_amdgcn_mfma_f32_16x16x32_bf16(A1_2, c2, acc1, 0, 0, 0);
        acc2 = __builtin_amdgcn_mfma_f32_16x16x32_bf16(A2_2, c2, acc2, 0, 0, 0);
        acc3 = __builtin_amdgcn_mfma_f32_16x16x32_bf16(A3_2, c2, acc3, 0, 0, 0);
        acc0 = __builtin_amdgcn_mfma_f32_16x16x32_bf16(A0_3, c3, acc0, 0, 0, 0);
        acc1 = __builtin_amdgcn_mfma_f32_16x16x32_bf16(A1_3, c3, acc1, 0, 0, 0);
        acc2 = __builtin_amdgcn_mfma_f32_16x16x32_bf16(A2_3, c3, acc2, 0, 0, 0);
        acc3 = __builtin_amdgcn_mfma_f32_16x16x32_bf16(A3_3, c3, acc3, 0, 0, 0);

        if (ccNow < CLASSES) {
            const float bias = fcb[ccNow];
            // C/D: col=lane&15, row=quad*4+r within each 16-row A-tile
            float* orow0 = out + (long)(bbase +  0 + quad * 4) * CLASSES + ccNow;
            float* orow1 = out + (long)(bbase + 16 + quad * 4) * CLASSES + ccNow;
            float* orow2 = out + (long)(bbase + 32 + quad * 4) * CLASSES + ccNow;
            float* orow3 = out + (long)(bbase + 48 + quad * 4) * CLASSES + ccNow;
#pragma unroll
            for (int r = 0; r < 4; ++r) {
                orow0[(long)r * CLASSES] = acc0[r] + bias;
                orow1[(long)r * CLASSES] = acc1[r] + bias;
                orow2[(long)r * CLASSES] = acc2[r] + bias;
                orow3[(long)r * CLASSES] = acc3[r] + bias;
            }
        }
    }
}

// ---------- f32 fallback (workspace too small for the i8 table) ----------
__global__ __launch_bounds__(256) void convert_fcw(const float* __restrict__ fcw,
                                                   unsigned short* __restrict__ wb) {
    long i = ((long)blockIdx.x * 256 + threadIdx.x) * 8;
    if (i >= (long)CLASSES * EMB) return;
    float4 v0 = *(const float4*)(fcw + i);
    float4 v1 = *(const float4*)(fcw + i + 4);
    uint4 o;
    o.x = (unsigned int)f32_to_bf16(v0.x) | ((unsigned int)f32_to_bf16(v0.y) << 16);
    o.y = (unsigned int)f32_to_bf16(v0.z) | ((unsigned int)f32_to_bf16(v0.w) << 16);
    o.z = (unsigned int)f32_to_bf16(v1.x) | ((unsigned int)f32_to_bf16(v1.y) << 16);
    o.w = (unsigned int)f32_to_bf16(v1.z) | ((unsigned int)f32_to_bf16(v1.w) << 16);
    *(uint4*)(wb + i) = o;
}

__global__ __launch_bounds__(256) void bag_pool_f32(const int* __restrict__ seq,
                                                    const float* __restrict__ emb,
                                                    unsigned short* __restrict__ pooled) {
    const int lane = threadIdx.x & 63;
    const int wid  = threadIdx.x >> 6;
    const int b    = blockIdx.x * 4 + wid;
    const int* srow = seq + (long)b * SEQLEN;
    int ids0 = srow[lane];
    int ids1 = srow[lane + 64];
    int ids2 = srow[lane + 128];
    int ids3 = (lane < 8) ? srow[lane + 192] : 0;
    const int half = lane >> 5;
    const int dsub = (lane & 31) * 4;
    float4 acc = {0.f, 0.f, 0.f, 0.f};
#define PAIR_BODY(IDS, Q)                                                   \
    {                                                                       \
        int tok = __shfl((IDS), 2 * (Q) + half);                            \
        if (tok != 0) {                                                     \
            float4 v = *(const float4*)(emb + (long)tok * EMB + dsub);      \
            acc.x += v.x; acc.y += v.y; acc.z += v.z; acc.w += v.w;         \
        }                                                                   \
    }
#pragma unroll 8
    for (int q = 0; q < 32; ++q) PAIR_BODY(ids0, q)
#pragma unroll 8
    for (int q = 0; q < 32; ++q) PAIR_BODY(ids1, q)
#pragma unroll 8
    for (int q = 0; q < 32; ++q) PAIR_BODY(ids2, q)
#pragma unroll
    for (int q = 0; q < 4; ++q)  PAIR_BODY(ids3, q)
#undef PAIR_BODY
    acc.x += __shfl_xor(acc.x, 32);
    acc.y += __shfl_xor(acc.y, 32);
    acc.z += __shfl_xor(acc.z, 32);
    acc.w += __shfl_xor(acc.w, 32);
    if (lane < 32) {
        uint2 o;
        o.x = (unsigned int)f32_to_bf16(acc.x) | ((unsigned int)f32_to_bf16(acc.y) << 16);
        o.y = (unsigned int)f32_to_bf16(acc.z) | ((unsigned int)f32_to_bf16(acc.w) << 16);
        *(uint2*)(pooled + (long)b * EMB + dsub) = o;
    }
}

__global__ __launch_bounds__(256) void bow_gemm(const unsigned short* __restrict__ pooled,
                                                const unsigned short* __restrict__ fcw,
                                                const float* __restrict__ fcb,
                                                float* __restrict__ out) {
    const int lane = threadIdx.x & 63;
    const int wid  = threadIdx.x >> 6;
    const int quad = lane >> 4;
    const int m0   = blockIdx.x * 64 + wid * 16;
    const int mrow = m0 + (lane & 15);
    const int koff = quad * 8;

    const unsigned short* ar = pooled + (long)mrow * EMB + koff;
    bf16x8 a0 = *(const bf16x8*)(ar + 0 * 32);
    bf16x8 a1 = *(const bf16x8*)(ar + 1 * 32);
    bf16x8 a2 = *(const bf16x8*)(ar + 2 * 32);
    bf16x8 a3 = *(const bf16x8*)(ar + 3 * 32);

    int ccur = (blockIdx.y * 21) * 16 + (lane & 15);
    const unsigned short* wr = fcw + (long)((ccur < CLASSES) ? ccur : 0) * EMB + koff;
    bf16x8 w0 = *(const bf16x8*)(wr + 0 * 32);
    bf16x8 w1 = *(const bf16x8*)(wr + 1 * 32);
    bf16x8 w2 = *(const bf16x8*)(wr + 2 * 32);
    bf16x8 w3 = *(const bf16x8*)(wr + 3 * 32);

#pragma unroll 1
    for (int i = 0; i < 21; ++i) {
        bf16x8 c0 = w0, c1 = w1, c2 = w2, c3 = w3;
        const int cc = ccur;
        if (i + 1 < 21) {
            ccur += 16;
            const unsigned short* wn = fcw + (long)((ccur < CLASSES) ? ccur : 0) * EMB + koff;
            w0 = *(const bf16x8*)(wn + 0 * 32);
            w1 = *(const bf16x8*)(wn + 1 * 32);
            w2 = *(const bf16x8*)(wn + 2 * 32);
            w3 = *(const bf16x8*)(wn + 3 * 32);
        }
        f32x4 acc = {0.f, 0.f, 0.f, 0.f};
        acc = __builtin_amdgcn_mfma_f32_16x16x32_bf16(a0, c0, acc, 0, 0, 0);
        acc = __builtin_amdgcn_mfma_f32_16x16x32_bf16(a1, c1, acc, 0, 0, 0);
        acc = __builtin_amdgcn_mfma_f32_16x16x32_bf16(a2, c2, acc, 0, 0, 0);
        acc = __builtin_amdgcn_mfma_f32_16x16x32_bf16(a3, c3, acc, 0, 0, 0);

        if (cc < CLASSES) {
            const float bias = fcb[cc];
            float* orow = out + (long)(m0 + quad * 4) * CLASSES + cc;
#pragma unroll
            for (int r = 0; r < 4; ++r)
                orow[(long)r * CLASSES] = acc[r] + bias;
        }
    }
}

extern "C" void kernel_launch(void* const* d_in, const int* in_sizes, int n_in,
                              void* d_out, int out_size, void* d_ws, size_t ws_size,
                              hipStream_t stream) {
    const int*   seq = (const int*)d_in[0];
    const float* emb = (const float*)d_in[1];   // f32 [VOCAB, EMB]
    const float* fcw = (const float*)d_in[2];   // f32 [CLASSES, EMB]
    const float* fcb = (const float*)d_in[3];   // f32 [CLASSES]
    float*       out = (float*)d_out;           // f32 [BATCH, CLASSES]

    // main-path workspace: scl | e8 | fcw_bf16
    float*          scl      = (float*)d_ws;                              // f32 [VOCAB]      400 KB
    unsigned char*  e8       = (unsigned char*)(scl + VOCAB);             // i8 [VOCAB,EMB]  12.8 MB
    unsigned short* fcw_bf16 = (unsigned short*)(e8 + (long)VOCAB * EMB); // bf16 [CLASSES,EMB] 256 KB

    const size_t need = (size_t)VOCAB * 4 + (size_t)VOCAB * EMB + (size_t)CLASSES * EMB * 2;

    if (ws_size >= need) {
        convert_emb_i8<<<6313, 256, 0, stream>>>(emb, fcw, e8, scl, fcw_bf16);
        pool_gemm_i8<<<BATCH / 64, 1024, 0, stream>>>(seq, e8, scl, fcw_bf16, fcb, out);
    } else {
        unsigned short* pooled  = (unsigned short*)d_ws;              // bf16 [BATCH, EMB] 4 MB
        unsigned short* fcw_bf  = pooled + (long)BATCH * EMB;         // bf16 [CLASSES, EMB]
        convert_fcw<<<63, 256, 0, stream>>>(fcw, fcw_bf);
        bag_pool_f32<<<BATCH / 4, 256, 0, stream>>>(seq, emb, pooled);
        bow_gemm<<<dim3(BATCH / 64, 3), 256, 0, stream>>>(pooled, fcw_bf, fcb, out);
    }
}